// Round 2
// baseline (152.786 us; speedup 1.0000x reference)
//
#include <hip/hip_runtime.h>

#define TT 8192
#define DD 64
#define MODS 4
#define NCH 256
#define CH  32    // TT / NCH
#define QPB 8     // queries per gather block

typedef __attribute__((ext_vector_type(8))) short bf16x8;
typedef __attribute__((ext_vector_type(4))) float f32x4;

// round-to-nearest-even fp32 -> bf16 bits
__device__ __forceinline__ unsigned f2bf1(float x) {
    unsigned u = __float_as_uint(x);
    return (u + 0x7FFFu + ((u >> 16) & 1u)) >> 16;
}
__device__ __forceinline__ unsigned packbf(float a, float b) {
    return f2bf1(a) | (f2bf1(b) << 16);
}

// stage one fp32 W layer [d][c] -> LDS bf16 W^T [c][d] (pitch 72 shorts).
__device__ __forceinline__ void stage_w(const float* __restrict__ Wl,
                                        unsigned short* wb, int c, int dp0)
{
    #pragma unroll
    for (int it = 0; it < 8; ++it) {
        int dp = dp0 + 4 * it;                    // 0..31 (pair of d's)
        float w0 = Wl[(2 * dp)     * DD + c];
        float w1 = Wl[(2 * dp + 1) * DD + c];
        *(unsigned*)&wb[c * 72 + 2 * dp] = packbf(w0, w1);
    }
}

// ---------------------------------------------------------------------------
// Kernel 1: fused MLP (bf16 MFMA) + chunk scan + time extraction + PREFIX.
// New this round: per-modality completion counters; the last-finishing block
// of each modality computes that modality's exclusive chunk prefix (PreC),
// absorbing kernel 2's prefix blocks (fence + atomic "last block" pattern).
// ---------------------------------------------------------------------------
__global__ __launch_bounds__(256)
void mlp_scan(const float* __restrict__ X,
              const float* __restrict__ wq_w, const float* __restrict__ wq_b,
              const float* __restrict__ wk_w, const float* __restrict__ wk_b,
              float* __restrict__ Q, float* __restrict__ Ctot,
              float* __restrict__ Crow, float* __restrict__ PreC,
              float* __restrict__ times, int* __restrict__ ctr)
{
    __shared__ unsigned short xbuf[4][16][72];   //  9,216 B
    __shared__ unsigned short wbuf[2][64][72];   // 18,432 B
    __shared__ float kbuf[64][68];               // 17,408 B
    __shared__ float2 vstash[64];                //    512 B
    __shared__ int   lastflag;
    __shared__ float hs[128];

    const int job = blockIdx.y;
    const float *xin, *Wj, *Bias;
    if (job == 0) { xin = X; Wj = wq_w; Bias = wq_b; }
    else {
        const int m = job - 1;
        xin  = X    + (size_t)m * TT * DD;
        Wj   = wk_w + (size_t)m * 3 * DD * DD;
        Bias = wk_b + (size_t)m * 3 * DD;
    }

    const int t    = threadIdx.x;
    const int wv   = t >> 6;
    const int lane = t & 63;
    const int quad = lane >> 4;
    const int l15  = lane & 15;
    const int row0 = blockIdx.x * 64 + wv * 16;   // this wave's 16 global rows
    unsigned short* xb = &xbuf[wv][0][0];
    const int wc = t & 63, wdp0 = t >> 6;

    // ---- stage this wave's 16x64 fp32 rows as bf16; stash fp32 V/time ----
    {
        const float4* src = (const float4*)(xin + (size_t)row0 * DD);
        #pragma unroll
        for (int k = 0; k < 4; ++k) {
            int f = lane + 64 * k;                // float4 idx 0..255
            int r = f >> 4, c4 = (f & 15) << 2;   // local-wave row, col
            float4 v = src[f];
            if (job > 0) {
                if ((f & 15) == 0)  vstash[wv * 16 + r] = make_float2(v.x, v.y);
                if ((f & 15) == 15) times[(size_t)(job - 1) * TT + row0 + r] = v.w;
            }
            uint2 p = make_uint2(packbf(v.x, v.y), packbf(v.z, v.w));
            *(uint2*)&xb[r * 72 + c4] = p;
        }
    }

    stage_w(Wj, &wbuf[0][0][0], wc, wdp0);

    #pragma unroll
    for (int l = 0; l < 3; ++l) {
        __syncthreads();
        const unsigned short* wb = &wbuf[l & 1][0][0];
        if (l < 2)
            stage_w(Wj + (size_t)(l + 1) * DD * DD, &wbuf[(l + 1) & 1][0][0], wc, wdp0);

        const float* Bl = Bias + l * DD;
        f32x4 acc[4];
        #pragma unroll
        for (int mt = 0; mt < 4; ++mt) {
            float4 b4 = *(const float4*)(Bl + 16 * mt + quad * 4);
            acc[mt][0] = b4.x; acc[mt][1] = b4.y; acc[mt][2] = b4.z; acc[mt][3] = b4.w;
        }

        bf16x8 xf[2];
        #pragma unroll
        for (int kt = 0; kt < 2; ++kt)
            xf[kt] = *(const bf16x8*)&xb[l15 * 72 + quad * 8 + kt * 32];

        #pragma unroll
        for (int mt = 0; mt < 4; ++mt) {
            #pragma unroll
            for (int kt = 0; kt < 2; ++kt) {
                bf16x8 wf = *(const bf16x8*)&wb[(16 * mt + l15) * 72 + quad * 8 + kt * 32];
                acc[mt] = __builtin_amdgcn_mfma_f32_16x16x32_bf16(wf, xf[kt], acc[mt], 0, 0, 0);
            }
        }

        if (l < 2) {
            #pragma unroll
            for (int mt = 0; mt < 4; ++mt) {
                float r0 = fmaxf(acc[mt][0], 0.f), r1 = fmaxf(acc[mt][1], 0.f);
                float r2 = fmaxf(acc[mt][2], 0.f), r3 = fmaxf(acc[mt][3], 0.f);
                uint2 p = make_uint2(packbf(r0, r1), packbf(r2, r3));
                *(uint2*)&xb[l15 * 72 + 16 * mt + quad * 4] = p;
            }
        } else {
            #pragma unroll
            for (int mt = 0; mt < 4; ++mt) {
                float4 v = make_float4(acc[mt][0], acc[mt][1], acc[mt][2], acc[mt][3]);
                if (job == 0)
                    *(float4*)(Q + (size_t)(row0 + l15) * DD + 16 * mt + quad * 4) = v;
                else
                    *(float4*)(&kbuf[wv * 16 + l15][16 * mt + quad * 4]) = v;
            }
        }
    }

    // ---- fused chunk scan (jobs 1..4): 2 chunks of 32 rows per block ----
    if (job > 0) {
        __syncthreads();                          // kbuf/vstash complete
        const int m    = job - 1;
        const int chl  = t >> 7;                  // 0..1: local chunk
        const int tid2 = t & 127;
        const int d = tid2 & 63, e = tid2 >> 6;
        const int ch = blockIdx.x * 2 + chl;      // global chunk 0..255
        const size_t rbase = ((size_t)m * TT + (size_t)ch * CH) * 128 + tid2;
        float acc = 0.f;
        #pragma unroll
        for (int j = 0; j < 4; ++j) {
            #pragma unroll
            for (int s = 0; s < 8; ++s) {
                const int r  = j * 8 + s;         // row within chunk 0..31
                const int rr = chl * 32 + r;
                float kv = kbuf[rr][d];
                float vv = e ? vstash[rr].y : vstash[rr].x;
                acc = fmaf(kv, vv, acc);
                Crow[rbase + (size_t)r * 128] = acc;
            }
        }
        Ctot[((size_t)m * NCH + ch) * 128 + tid2] = acc;

        // ---- last block of this modality computes its exclusive prefix ----
        __threadfence();                          // publish my Ctot stores
        __syncthreads();                          // all threads fenced
        if (t == 0)
            lastflag = (atomicAdd(&ctr[m], 1) == gridDim.x - 1);
        __syncthreads();
        if (lastflag) {
            __threadfence();                      // acquire others' stores
            const int sub = t >> 7, tl = t & 127;
            const size_t base = ((size_t)m * NCH + (size_t)sub * 128) * 128 + tl;

            // pass A: this half's total — independent loads, serial adds only
            float tot = 0.f;
            #pragma unroll 8
            for (int c = 0; c < 128; ++c)
                tot += Ctot[base + (size_t)c * 128];
            if (sub == 0) hs[tl] = tot;
            __syncthreads();

            // pass B: exclusive prefix writes, batched 8-wide reloads (L2-hot)
            float run = sub ? hs[tl] : 0.f;
            #pragma unroll 1
            for (int bb = 0; bb < 16; ++bb) {
                float v[8];
                #pragma unroll
                for (int i = 0; i < 8; ++i)
                    v[i] = Ctot[base + (size_t)(bb * 8 + i) * 128];
                #pragma unroll
                for (int i = 0; i < 8; ++i) {
                    PreC[base + (size_t)(bb * 8 + i) * 128] = run;
                    run += v[i];
                }
            }
        }
    }
}

// ---------------------------------------------------------------------------
// Kernel 2 (was kernel 3): gather with inlined binary search.
// Phase 0: lanes 0..31 run the 13-step searches for this block's 8 q x 4 m
//          (L2-hot times), share idx via LDS — the idx buffer and the whole
//          prefix_find kernel are gone.
// Main:    S[idx] = PreC[chunk(idx)] + Crow[idx]; 8 queries per block.
// ---------------------------------------------------------------------------
__global__ __launch_bounds__(256)
void gather_kernel(const float* __restrict__ Q,
                   const float* __restrict__ Crow,
                   const float* __restrict__ PreC,
                   const float* __restrict__ times,
                   float* __restrict__ out)
{
    const int bx   = blockIdx.x;                  // 0..1023
    // XCD-contiguous q ranges: each XCD owns 1024 consecutive queries.
    const int q0   = ((bx & 7) << 10) | ((bx >> 3) << 3);

    __shared__ int   idxs[QPB][MODS];
    __shared__ float red[QPB][MODS][2];

    if (threadIdx.x < QPB * MODS) {
        const int u = threadIdx.x >> 2, mm = threadIdx.x & 3;
        const float t1 = times[q0 + u];           // modality-0 row IS t1
        const float* t2 = times + (size_t)mm * TT;
        int lo = 0, hi = TT;
        #pragma unroll 1
        for (int s = 0; s < 13; ++s) {            // 2^13 == TT
            int mid = (lo + hi) >> 1;
            bool le = (t2[mid] <= t1);
            lo = le ? mid + 1 : lo;
            hi = le ? hi : mid;
        }
        idxs[u][mm] = lo - 1;                     // searchsorted(right) - 1
    }
    __syncthreads();

    const int m    = threadIdx.x >> 6;
    const int lane = threadIdx.x & 63;

    #pragma unroll
    for (int u = 0; u < QPB; ++u) {
        const int q  = q0 + u;
        const int id = idxs[u][m];                // wave-uniform
        float a0 = 0.f, a1 = 0.f;
        if (id >= 0) {
            const float qv = Q[(size_t)q * DD + lane];
            const int cg = id >> 5;               // chunk 0..255
            const float* P = PreC + ((size_t)(m * NCH + cg) << 7);
            const float* R = Crow + (((size_t)m * TT + id) << 7);
            float s0 = P[lane]      + R[lane];
            float s1 = P[64 + lane] + R[64 + lane];
            a0 = qv * s0;
            a1 = qv * s1;
        }
        #pragma unroll
        for (int off = 32; off > 0; off >>= 1) {
            a0 += __shfl_xor(a0, off, 64);
            a1 += __shfl_xor(a1, off, 64);
        }
        if (lane == 0) { red[u][m][0] = a0; red[u][m][1] = a1; }
    }
    __syncthreads();
    if (threadIdx.x < QPB * 2) {
        const int u = threadIdx.x >> 1, e = threadIdx.x & 1;
        out[((q0 + u) << 1) + e] =
            red[u][0][e] + red[u][1][e] + red[u][2][e] + red[u][3][e];
    }
}

extern "C" void kernel_launch(void* const* d_in, const int* in_sizes, int n_in,
                              void* d_out, int out_size, void* d_ws, size_t ws_size,
                              hipStream_t stream)
{
    const float* X    = (const float*)d_in[0];
    const float* wq_w = (const float*)d_in[1];
    const float* wq_b = (const float*)d_in[2];
    const float* wk_w = (const float*)d_in[3];
    const float* wk_b = (const float*)d_in[4];
    float* out = (float*)d_out;

    float* ws    = (float*)d_ws;
    float* Q     = ws;                                    // TT*DD            (2 MB)
    float* Crow  = Q     + (size_t)TT * DD;               // MODS*TT*128      (16 MB)
    float* Ctot  = Crow  + (size_t)MODS * TT * 128;       // MODS*NCH*128     (512 KB)
    float* PreC  = Ctot  + (size_t)MODS * NCH * 128;      // MODS*NCH*128     (512 KB)
    float* times = PreC  + (size_t)MODS * NCH * 128;      // MODS*TT          (128 KB)
    int*   ctr   = (int*)(times + (size_t)MODS * TT);     // MODS ints

    hipMemsetAsync(ctr, 0, MODS * sizeof(int), stream);
    mlp_scan     <<<dim3(128, 5), 256, 0, stream>>>(X, wq_w, wq_b, wk_w, wk_b,
                                                    Q, Ctot, Crow, PreC, times, ctr);
    gather_kernel<<<TT / QPB,     256, 0, stream>>>(Q, Crow, PreC, times, out);
}

// Round 3
// 87.940 us; speedup vs baseline: 1.7374x; 1.7374x over previous
//
#include <hip/hip_runtime.h>

#define TT 8192
#define DD 64
#define MODS 4
#define NCH 256
#define CH  32    // TT / NCH
#define QPB 8     // queries per gather block

typedef __attribute__((ext_vector_type(8))) short bf16x8;
typedef __attribute__((ext_vector_type(4))) float f32x4;

// round-to-nearest-even fp32 -> bf16 bits
__device__ __forceinline__ unsigned f2bf1(float x) {
    unsigned u = __float_as_uint(x);
    return (u + 0x7FFFu + ((u >> 16) & 1u)) >> 16;
}
__device__ __forceinline__ unsigned packbf(float a, float b) {
    return f2bf1(a) | (f2bf1(b) << 16);
}

// stage one fp32 W layer [d][c] -> LDS bf16 W^T [c][d] (pitch 72 shorts).
__device__ __forceinline__ void stage_w(const float* __restrict__ Wl,
                                        unsigned short* wb, int c, int dp0)
{
    #pragma unroll
    for (int it = 0; it < 8; ++it) {
        int dp = dp0 + 4 * it;                    // 0..31 (pair of d's)
        float w0 = Wl[(2 * dp)     * DD + c];
        float w1 = Wl[(2 * dp + 1) * DD + c];
        *(unsigned*)&wb[c * 72 + 2 * dp] = packbf(w0, w1);
    }
}

// ---------------------------------------------------------------------------
// Kernel 1: fused MLP (bf16 MFMA) + chunk scan + time extraction.
// REVERTED to round-1 fire-and-forget form: the round-2 device-fence +
// atomic "last block" prefix fusion forced a per-block L2-writeback drain
// (80 us/dispatch). No fences here; all stores are fire-and-forget.
// ---------------------------------------------------------------------------
__global__ __launch_bounds__(256)
void mlp_scan(const float* __restrict__ X,
              const float* __restrict__ wq_w, const float* __restrict__ wq_b,
              const float* __restrict__ wk_w, const float* __restrict__ wk_b,
              float* __restrict__ Q, float* __restrict__ Ctot,
              float* __restrict__ Crow, float* __restrict__ times)
{
    __shared__ unsigned short xbuf[4][16][72];   //  9,216 B
    __shared__ unsigned short wbuf[2][64][72];   // 18,432 B
    __shared__ float kbuf[64][68];               // 17,408 B
    __shared__ float2 vstash[64];                //    512 B

    const int job = blockIdx.y;
    const float *xin, *Wj, *Bias;
    if (job == 0) { xin = X; Wj = wq_w; Bias = wq_b; }
    else {
        const int m = job - 1;
        xin  = X    + (size_t)m * TT * DD;
        Wj   = wk_w + (size_t)m * 3 * DD * DD;
        Bias = wk_b + (size_t)m * 3 * DD;
    }

    const int t    = threadIdx.x;
    const int wv   = t >> 6;
    const int lane = t & 63;
    const int quad = lane >> 4;
    const int l15  = lane & 15;
    const int row0 = blockIdx.x * 64 + wv * 16;   // this wave's 16 global rows
    unsigned short* xb = &xbuf[wv][0][0];
    const int wc = t & 63, wdp0 = t >> 6;

    // ---- stage this wave's 16x64 fp32 rows as bf16; stash fp32 V/time ----
    {
        const float4* src = (const float4*)(xin + (size_t)row0 * DD);
        #pragma unroll
        for (int k = 0; k < 4; ++k) {
            int f = lane + 64 * k;                // float4 idx 0..255
            int r = f >> 4, c4 = (f & 15) << 2;   // local-wave row, col
            float4 v = src[f];
            if (job > 0) {
                if ((f & 15) == 0)  vstash[wv * 16 + r] = make_float2(v.x, v.y);
                if ((f & 15) == 15) times[(size_t)(job - 1) * TT + row0 + r] = v.w;
            }
            uint2 p = make_uint2(packbf(v.x, v.y), packbf(v.z, v.w));
            *(uint2*)&xb[r * 72 + c4] = p;
        }
    }

    stage_w(Wj, &wbuf[0][0][0], wc, wdp0);

    #pragma unroll
    for (int l = 0; l < 3; ++l) {
        __syncthreads();
        const unsigned short* wb = &wbuf[l & 1][0][0];
        if (l < 2)
            stage_w(Wj + (size_t)(l + 1) * DD * DD, &wbuf[(l + 1) & 1][0][0], wc, wdp0);

        const float* Bl = Bias + l * DD;
        f32x4 acc[4];
        #pragma unroll
        for (int mt = 0; mt < 4; ++mt) {
            float4 b4 = *(const float4*)(Bl + 16 * mt + quad * 4);
            acc[mt][0] = b4.x; acc[mt][1] = b4.y; acc[mt][2] = b4.z; acc[mt][3] = b4.w;
        }

        bf16x8 xf[2];
        #pragma unroll
        for (int kt = 0; kt < 2; ++kt)
            xf[kt] = *(const bf16x8*)&xb[l15 * 72 + quad * 8 + kt * 32];

        #pragma unroll
        for (int mt = 0; mt < 4; ++mt) {
            #pragma unroll
            for (int kt = 0; kt < 2; ++kt) {
                bf16x8 wf = *(const bf16x8*)&wb[(16 * mt + l15) * 72 + quad * 8 + kt * 32];
                acc[mt] = __builtin_amdgcn_mfma_f32_16x16x32_bf16(wf, xf[kt], acc[mt], 0, 0, 0);
            }
        }

        if (l < 2) {
            #pragma unroll
            for (int mt = 0; mt < 4; ++mt) {
                float r0 = fmaxf(acc[mt][0], 0.f), r1 = fmaxf(acc[mt][1], 0.f);
                float r2 = fmaxf(acc[mt][2], 0.f), r3 = fmaxf(acc[mt][3], 0.f);
                uint2 p = make_uint2(packbf(r0, r1), packbf(r2, r3));
                *(uint2*)&xb[l15 * 72 + 16 * mt + quad * 4] = p;
            }
        } else {
            #pragma unroll
            for (int mt = 0; mt < 4; ++mt) {
                float4 v = make_float4(acc[mt][0], acc[mt][1], acc[mt][2], acc[mt][3]);
                if (job == 0)
                    *(float4*)(Q + (size_t)(row0 + l15) * DD + 16 * mt + quad * 4) = v;
                else
                    *(float4*)(&kbuf[wv * 16 + l15][16 * mt + quad * 4]) = v;
            }
        }
    }

    // ---- fused chunk scan (jobs 1..4): 2 chunks of 32 rows per block ----
    // Stores the inclusive per-row prefix (Crow) every row; Ctot at the end.
    if (job > 0) {
        __syncthreads();                          // kbuf/vstash complete
        const int m    = job - 1;
        const int chl  = t >> 7;                  // 0..1: local chunk
        const int tid2 = t & 127;
        const int d = tid2 & 63, e = tid2 >> 6;
        const int ch = blockIdx.x * 2 + chl;      // global chunk 0..255
        const size_t rbase = ((size_t)m * TT + (size_t)ch * CH) * 128 + tid2;
        float acc = 0.f;
        #pragma unroll
        for (int j = 0; j < 4; ++j) {
            #pragma unroll
            for (int s = 0; s < 8; ++s) {
                const int r  = j * 8 + s;         // row within chunk 0..31
                const int rr = chl * 32 + r;
                float kv = kbuf[rr][d];
                float vv = e ? vstash[rr].y : vstash[rr].x;
                acc = fmaf(kv, vv, acc);
                Crow[rbase + (size_t)r * 128] = acc;
            }
        }
        Ctot[((size_t)m * NCH + ch) * 128 + tid2] = acc;
    }
}

// ---------------------------------------------------------------------------
// Kernel 2: exclusive chunk prefix only (search moved into gather).
// 4 blocks (one per modality) x 1024 threads, 8 subs x 128 lanes.
// Each sub keeps its 32 chunk values IN REGISTERS: pass A loads once and
// sums; pass B reuses the registers for the prefix stores (no reload).
// ---------------------------------------------------------------------------
__global__ __launch_bounds__(1024)
void prefix_kernel(const float* __restrict__ Ctot, float* __restrict__ PreC)
{
    __shared__ float hs[8][128];
    const int m   = blockIdx.x;
    const int sub = threadIdx.x >> 7;             // 0..7
    const int tl  = threadIdx.x & 127;
    const size_t base = ((size_t)m * NCH + (size_t)sub * 32) * 128 + tl;

    float v[32];
    #pragma unroll
    for (int c = 0; c < 32; ++c)
        v[c] = Ctot[base + (size_t)c * 128];      // 32 independent loads
    float tot = 0.f;
    #pragma unroll
    for (int c = 0; c < 32; ++c) tot += v[c];
    hs[sub][tl] = tot;
    __syncthreads();

    float run = 0.f;
    #pragma unroll
    for (int s = 0; s < 7; ++s)
        if (s < sub) run += hs[s][tl];
    #pragma unroll
    for (int c = 0; c < 32; ++c) {
        PreC[base + (size_t)c * 128] = run;       // exclusive prefix
        run += v[c];
    }
}

// ---------------------------------------------------------------------------
// Kernel 3: gather with inlined binary search (kept from round 2 — it was
// not implicated in the regression).
// Phase 0: lanes 0..31 run the 13-step searches for this block's 8 q x 4 m
//          (L2-hot times), share idx via LDS.
// Main:    S[idx] = PreC[chunk(idx)] + Crow[idx]; 8 queries per block.
// ---------------------------------------------------------------------------
__global__ __launch_bounds__(256)
void gather_kernel(const float* __restrict__ Q,
                   const float* __restrict__ Crow,
                   const float* __restrict__ PreC,
                   const float* __restrict__ times,
                   float* __restrict__ out)
{
    const int bx   = blockIdx.x;                  // 0..1023
    // XCD-contiguous q ranges: each XCD owns 1024 consecutive queries.
    const int q0   = ((bx & 7) << 10) | ((bx >> 3) << 3);

    __shared__ int   idxs[QPB][MODS];
    __shared__ float red[QPB][MODS][2];

    if (threadIdx.x < QPB * MODS) {
        const int u = threadIdx.x >> 2, mm = threadIdx.x & 3;
        const float t1 = times[q0 + u];           // modality-0 row IS t1
        const float* t2 = times + (size_t)mm * TT;
        int lo = 0, hi = TT;
        #pragma unroll 1
        for (int s = 0; s < 13; ++s) {            // 2^13 == TT
            int mid = (lo + hi) >> 1;
            bool le = (t2[mid] <= t1);
            lo = le ? mid + 1 : lo;
            hi = le ? hi : mid;
        }
        idxs[u][mm] = lo - 1;                     // searchsorted(right) - 1
    }
    __syncthreads();

    const int m    = threadIdx.x >> 6;
    const int lane = threadIdx.x & 63;

    #pragma unroll
    for (int u = 0; u < QPB; ++u) {
        const int q  = q0 + u;
        const int id = idxs[u][m];                // wave-uniform
        float a0 = 0.f, a1 = 0.f;
        if (id >= 0) {
            const float qv = Q[(size_t)q * DD + lane];
            const int cg = id >> 5;               // chunk 0..255
            const float* P = PreC + ((size_t)(m * NCH + cg) << 7);
            const float* R = Crow + (((size_t)m * TT + id) << 7);
            float s0 = P[lane]      + R[lane];
            float s1 = P[64 + lane] + R[64 + lane];
            a0 = qv * s0;
            a1 = qv * s1;
        }
        #pragma unroll
        for (int off = 32; off > 0; off >>= 1) {
            a0 += __shfl_xor(a0, off, 64);
            a1 += __shfl_xor(a1, off, 64);
        }
        if (lane == 0) { red[u][m][0] = a0; red[u][m][1] = a1; }
    }
    __syncthreads();
    if (threadIdx.x < QPB * 2) {
        const int u = threadIdx.x >> 1, e = threadIdx.x & 1;
        out[((q0 + u) << 1) + e] =
            red[u][0][e] + red[u][1][e] + red[u][2][e] + red[u][3][e];
    }
}

extern "C" void kernel_launch(void* const* d_in, const int* in_sizes, int n_in,
                              void* d_out, int out_size, void* d_ws, size_t ws_size,
                              hipStream_t stream)
{
    const float* X    = (const float*)d_in[0];
    const float* wq_w = (const float*)d_in[1];
    const float* wq_b = (const float*)d_in[2];
    const float* wk_w = (const float*)d_in[3];
    const float* wk_b = (const float*)d_in[4];
    float* out = (float*)d_out;

    float* ws    = (float*)d_ws;
    float* Q     = ws;                                    // TT*DD            (2 MB)
    float* Crow  = Q     + (size_t)TT * DD;               // MODS*TT*128      (16 MB)
    float* Ctot  = Crow  + (size_t)MODS * TT * 128;       // MODS*NCH*128     (512 KB)
    float* PreC  = Ctot  + (size_t)MODS * NCH * 128;      // MODS*NCH*128     (512 KB)
    float* times = PreC  + (size_t)MODS * NCH * 128;      // MODS*TT          (128 KB)

    mlp_scan     <<<dim3(128, 5), 256,  0, stream>>>(X, wq_w, wq_b, wk_w, wk_b,
                                                     Q, Ctot, Crow, times);
    prefix_kernel<<<MODS,         1024, 0, stream>>>(Ctot, PreC);
    gather_kernel<<<TT / QPB,     256,  0, stream>>>(Q, Crow, PreC, times, out);
}

// Round 4
// 87.480 us; speedup vs baseline: 1.7465x; 1.0053x over previous
//
#include <hip/hip_runtime.h>

#define TT 8192
#define DD 64
#define MODS 4
#define NCH 256
#define CH  32    // TT / NCH
#define QPB 8     // queries per gather block

typedef __attribute__((ext_vector_type(8))) short bf16x8;
typedef __attribute__((ext_vector_type(4))) float f32x4;

// round-to-nearest-even fp32 -> bf16 bits
__device__ __forceinline__ unsigned f2bf1(float x) {
    unsigned u = __float_as_uint(x);
    return (u + 0x7FFFu + ((u >> 16) & 1u)) >> 16;
}
__device__ __forceinline__ unsigned packbf(float a, float b) {
    return f2bf1(a) | (f2bf1(b) << 16);
}

// stage one fp32 W layer [d][c] -> LDS bf16 W^T [c][d] (pitch 72 shorts).
__device__ __forceinline__ void stage_w(const float* __restrict__ Wl,
                                        unsigned short* wb, int c, int dp0)
{
    #pragma unroll
    for (int it = 0; it < 8; ++it) {
        int dp = dp0 + 4 * it;                    // 0..31 (pair of d's)
        float w0 = Wl[(2 * dp)     * DD + c];
        float w1 = Wl[(2 * dp + 1) * DD + c];
        *(unsigned*)&wb[c * 72 + 2 * dp] = packbf(w0, w1);
    }
}

// ---------------------------------------------------------------------------
// Kernel 1: fused MLP (bf16 MFMA) + chunk scan + time extraction.
// This round: kbuf (scan-phase K values, 17.4 KB) is OVERLAID on wbuf
// (weights, dead after the l=2 fragment reads) via a union + one extra
// __syncthreads() at the l=2 epilogue. LDS 46.6 KB -> 28.2 KB, so
// 5 blocks/CU fit and the whole 640-block grid is co-resident (the kernel
// is latency/occupancy-bound: r2 counters showed 15% occupancy, 4% HBM).
// ---------------------------------------------------------------------------
__global__ __launch_bounds__(256)
void mlp_scan(const float* __restrict__ X,
              const float* __restrict__ wq_w, const float* __restrict__ wq_b,
              const float* __restrict__ wk_w, const float* __restrict__ wk_b,
              float* __restrict__ Q, float* __restrict__ Ctot,
              float* __restrict__ Crow, float* __restrict__ times)
{
    __shared__ unsigned short xbuf[4][16][72];   //  9,216 B
    __shared__ union {
        unsigned short w[2][64][72];             // 18,432 B (layers)
        float          k[64][68];                // 17,408 B (scan phase)
    } wk;
    __shared__ float2 vstash[64];                //    512 B

    const int job = blockIdx.y;
    const float *xin, *Wj, *Bias;
    if (job == 0) { xin = X; Wj = wq_w; Bias = wq_b; }
    else {
        const int m = job - 1;
        xin  = X    + (size_t)m * TT * DD;
        Wj   = wk_w + (size_t)m * 3 * DD * DD;
        Bias = wk_b + (size_t)m * 3 * DD;
    }

    const int t    = threadIdx.x;
    const int wv   = t >> 6;
    const int lane = t & 63;
    const int quad = lane >> 4;
    const int l15  = lane & 15;
    const int row0 = blockIdx.x * 64 + wv * 16;   // this wave's 16 global rows
    unsigned short* xb = &xbuf[wv][0][0];
    const int wc = t & 63, wdp0 = t >> 6;

    // ---- stage this wave's 16x64 fp32 rows as bf16; stash fp32 V/time ----
    {
        const float4* src = (const float4*)(xin + (size_t)row0 * DD);
        #pragma unroll
        for (int k = 0; k < 4; ++k) {
            int f = lane + 64 * k;                // float4 idx 0..255
            int r = f >> 4, c4 = (f & 15) << 2;   // local-wave row, col
            float4 v = src[f];
            if (job > 0) {
                if ((f & 15) == 0)  vstash[wv * 16 + r] = make_float2(v.x, v.y);
                if ((f & 15) == 15) times[(size_t)(job - 1) * TT + row0 + r] = v.w;
            }
            uint2 p = make_uint2(packbf(v.x, v.y), packbf(v.z, v.w));
            *(uint2*)&xb[r * 72 + c4] = p;
        }
    }

    stage_w(Wj, &wk.w[0][0][0], wc, wdp0);

    #pragma unroll
    for (int l = 0; l < 3; ++l) {
        __syncthreads();
        const unsigned short* wb = &wk.w[l & 1][0][0];
        if (l < 2)
            stage_w(Wj + (size_t)(l + 1) * DD * DD, &wk.w[(l + 1) & 1][0][0], wc, wdp0);

        const float* Bl = Bias + l * DD;
        f32x4 acc[4];
        #pragma unroll
        for (int mt = 0; mt < 4; ++mt) {
            float4 b4 = *(const float4*)(Bl + 16 * mt + quad * 4);
            acc[mt][0] = b4.x; acc[mt][1] = b4.y; acc[mt][2] = b4.z; acc[mt][3] = b4.w;
        }

        bf16x8 xf[2];
        #pragma unroll
        for (int kt = 0; kt < 2; ++kt)
            xf[kt] = *(const bf16x8*)&xb[l15 * 72 + quad * 8 + kt * 32];

        #pragma unroll
        for (int mt = 0; mt < 4; ++mt) {
            #pragma unroll
            for (int kt = 0; kt < 2; ++kt) {
                bf16x8 wf = *(const bf16x8*)&wb[(16 * mt + l15) * 72 + quad * 8 + kt * 32];
                acc[mt] = __builtin_amdgcn_mfma_f32_16x16x32_bf16(wf, xf[kt], acc[mt], 0, 0, 0);
            }
        }

        if (l < 2) {
            #pragma unroll
            for (int mt = 0; mt < 4; ++mt) {
                float r0 = fmaxf(acc[mt][0], 0.f), r1 = fmaxf(acc[mt][1], 0.f);
                float r2 = fmaxf(acc[mt][2], 0.f), r3 = fmaxf(acc[mt][3], 0.f);
                uint2 p = make_uint2(packbf(r0, r1), packbf(r2, r3));
                *(uint2*)&xb[l15 * 72 + 16 * mt + quad * 4] = p;
            }
        } else {
            // all waves must finish their wbuf fragment reads before kbuf
            // (which overlays wbuf) is written.
            __syncthreads();
            #pragma unroll
            for (int mt = 0; mt < 4; ++mt) {
                float4 v = make_float4(acc[mt][0], acc[mt][1], acc[mt][2], acc[mt][3]);
                if (job == 0)
                    *(float4*)(Q + (size_t)(row0 + l15) * DD + 16 * mt + quad * 4) = v;
                else
                    *(float4*)(&wk.k[wv * 16 + l15][16 * mt + quad * 4]) = v;
            }
        }
    }

    // ---- fused chunk scan (jobs 1..4): 2 chunks of 32 rows per block ----
    // Stores the inclusive per-row prefix (Crow) every row; Ctot at the end.
    if (job > 0) {
        __syncthreads();                          // kbuf/vstash complete
        const int m    = job - 1;
        const int chl  = t >> 7;                  // 0..1: local chunk
        const int tid2 = t & 127;
        const int d = tid2 & 63, e = tid2 >> 6;
        const int ch = blockIdx.x * 2 + chl;      // global chunk 0..255
        const size_t rbase = ((size_t)m * TT + (size_t)ch * CH) * 128 + tid2;
        float acc = 0.f;
        #pragma unroll
        for (int j = 0; j < 4; ++j) {
            #pragma unroll
            for (int s = 0; s < 8; ++s) {
                const int r  = j * 8 + s;         // row within chunk 0..31
                const int rr = chl * 32 + r;
                float kv = wk.k[rr][d];
                float vv = e ? vstash[rr].y : vstash[rr].x;
                acc = fmaf(kv, vv, acc);
                Crow[rbase + (size_t)r * 128] = acc;
            }
        }
        Ctot[((size_t)m * NCH + ch) * 128 + tid2] = acc;
    }
}

// ---------------------------------------------------------------------------
// Kernel 2: exclusive chunk prefix, spread over 32 blocks (was 4).
// Block = (modality, col-group of 16 cols); 256 threads = 16 subs x 16 cols.
// Each thread keeps its 16 chunk values in registers (load once, no reload).
// ---------------------------------------------------------------------------
__global__ __launch_bounds__(256)
void prefix_kernel(const float* __restrict__ Ctot, float* __restrict__ PreC)
{
    __shared__ float hs[16][16];
    const int m   = blockIdx.x >> 3;              // 0..3
    const int cg  = blockIdx.x & 7;               // col group 0..7
    const int sub = threadIdx.x >> 4;             // 0..15: chunk group
    const int cl  = threadIdx.x & 15;             // 0..15
    const int col = cg * 16 + cl;                 // 0..127
    const size_t base = ((size_t)m * NCH + (size_t)sub * 16) * 128 + col;

    float v[16];
    #pragma unroll
    for (int c = 0; c < 16; ++c)
        v[c] = Ctot[base + (size_t)c * 128];      // 16 independent loads
    float tot = 0.f;
    #pragma unroll
    for (int c = 0; c < 16; ++c) tot += v[c];
    hs[sub][cl] = tot;
    __syncthreads();

    float run = 0.f;
    #pragma unroll
    for (int s = 0; s < 15; ++s)
        if (s < sub) run += hs[s][cl];
    #pragma unroll
    for (int c = 0; c < 16; ++c) {
        PreC[base + (size_t)c * 128] = run;       // exclusive prefix
        run += v[c];
    }
}

// ---------------------------------------------------------------------------
// Kernel 3: gather with inlined binary search (unchanged from round 3).
// ---------------------------------------------------------------------------
__global__ __launch_bounds__(256)
void gather_kernel(const float* __restrict__ Q,
                   const float* __restrict__ Crow,
                   const float* __restrict__ PreC,
                   const float* __restrict__ times,
                   float* __restrict__ out)
{
    const int bx   = blockIdx.x;                  // 0..1023
    // XCD-contiguous q ranges: each XCD owns 1024 consecutive queries.
    const int q0   = ((bx & 7) << 10) | ((bx >> 3) << 3);

    __shared__ int   idxs[QPB][MODS];
    __shared__ float red[QPB][MODS][2];

    if (threadIdx.x < QPB * MODS) {
        const int u = threadIdx.x >> 2, mm = threadIdx.x & 3;
        const float t1 = times[q0 + u];           // modality-0 row IS t1
        const float* t2 = times + (size_t)mm * TT;
        int lo = 0, hi = TT;
        #pragma unroll 1
        for (int s = 0; s < 13; ++s) {            // 2^13 == TT
            int mid = (lo + hi) >> 1;
            bool le = (t2[mid] <= t1);
            lo = le ? mid + 1 : lo;
            hi = le ? hi : mid;
        }
        idxs[u][mm] = lo - 1;                     // searchsorted(right) - 1
    }
    __syncthreads();

    const int m    = threadIdx.x >> 6;
    const int lane = threadIdx.x & 63;

    #pragma unroll
    for (int u = 0; u < QPB; ++u) {
        const int q  = q0 + u;
        const int id = idxs[u][m];                // wave-uniform
        float a0 = 0.f, a1 = 0.f;
        if (id >= 0) {
            const float qv = Q[(size_t)q * DD + lane];
            const int cg = id >> 5;               // chunk 0..255
            const float* P = PreC + ((size_t)(m * NCH + cg) << 7);
            const float* R = Crow + (((size_t)m * TT + id) << 7);
            float s0 = P[lane]      + R[lane];
            float s1 = P[64 + lane] + R[64 + lane];
            a0 = qv * s0;
            a1 = qv * s1;
        }
        #pragma unroll
        for (int off = 32; off > 0; off >>= 1) {
            a0 += __shfl_xor(a0, off, 64);
            a1 += __shfl_xor(a1, off, 64);
        }
        if (lane == 0) { red[u][m][0] = a0; red[u][m][1] = a1; }
    }
    __syncthreads();
    if (threadIdx.x < QPB * 2) {
        const int u = threadIdx.x >> 1, e = threadIdx.x & 1;
        out[((q0 + u) << 1) + e] =
            red[u][0][e] + red[u][1][e] + red[u][2][e] + red[u][3][e];
    }
}

extern "C" void kernel_launch(void* const* d_in, const int* in_sizes, int n_in,
                              void* d_out, int out_size, void* d_ws, size_t ws_size,
                              hipStream_t stream)
{
    const float* X    = (const float*)d_in[0];
    const float* wq_w = (const float*)d_in[1];
    const float* wq_b = (const float*)d_in[2];
    const float* wk_w = (const float*)d_in[3];
    const float* wk_b = (const float*)d_in[4];
    float* out = (float*)d_out;

    float* ws    = (float*)d_ws;
    float* Q     = ws;                                    // TT*DD            (2 MB)
    float* Crow  = Q     + (size_t)TT * DD;               // MODS*TT*128      (16 MB)
    float* Ctot  = Crow  + (size_t)MODS * TT * 128;       // MODS*NCH*128     (512 KB)
    float* PreC  = Ctot  + (size_t)MODS * NCH * 128;      // MODS*NCH*128     (512 KB)
    float* times = PreC  + (size_t)MODS * NCH * 128;      // MODS*TT          (128 KB)

    mlp_scan     <<<dim3(128, 5), 256, 0, stream>>>(X, wq_w, wq_b, wk_w, wk_b,
                                                    Q, Ctot, Crow, times);
    prefix_kernel<<<MODS * 8,     256, 0, stream>>>(Ctot, PreC);
    gather_kernel<<<TT / QPB,     256, 0, stream>>>(Q, Crow, PreC, times, out);
}